// Round 9
// baseline (384.448 us; speedup 1.0000x reference)
//
#include <hip/hip_runtime.h>
#include <stdint.h>

#define N_NODES    50000
#define K_MAX      10
#define BATCH      64
#define T_STEPS    32
#define N_INPUTS   16
#define INPUT_BITS 64

#define NPW   224                 // nodes per workgroup
#define NWG   224                 // 14 groups x 16; NPW*NWG = 50176 >= 50000
#define NTHR  896                 // 4 threads (batch quarters) per node = 14 waves
#define GRPN  14                  // barrier tree: 14 groups
#define GRP_SZ 16                 //   of 16 WGs each
#define NBUF  (T_STEPS + 1)       // state ring: step t reads buf[t], writes buf[t+1]

#define BUF_STRIDE_B 400128u      // bytes per state buffer (50001*8 -> 128B aligned)

// ---------------- workspace layout (bytes) ----------------
#define OFF_BUFS   0u
#define OFF_XMASK  13204224u      // uint64[32*64]
#define OFF_GCTR   13220608u      // 32 steps x 14 group ctrs, each on own 256B line
#define OFF_RCTR   13335296u      // 32 root ctrs, each on own 256B line
#define OFF_PLUT   13343488u      // uint8[50176*128] packed LUT
// total ~19.77 MB

// ---------------- prep: init ring head, xor masks, sentinels, barrier ctrs ----------------
__global__ void prep_kernel(const int* __restrict__ x,
                            const int* __restrict__ init_states,
                            const int* __restrict__ input_nodes,
                            uint64_t* __restrict__ bufs,
                            uint64_t* __restrict__ xmask,
                            uint32_t* __restrict__ gctr,
                            uint32_t* __restrict__ rctr) {
    const int gid = blockIdx.x * blockDim.x + threadIdx.x;
    const size_t strw = BUF_STRIDE_B / 8;
    if (gid < N_NODES) {
        int n = gid;
        // last occurrence of n in input_nodes (last-write-wins scatter semantics)
        int jm = -1;
        for (int j = 0; j < INPUT_BITS; ++j)
            if (input_nodes[j] == n) jm = j;
        uint64_t v = init_states[n] ? ~0ull : 0ull;   // same init for all 64 batches
        if (jm >= 0) {
            uint64_t m = 0ull;
            for (int b = 0; b < BATCH; ++b)
                m |= (uint64_t)(x[b * (T_STEPS * INPUT_BITS) + jm] & 1) << b;  // t = 0
            v ^= m;
        }
        bufs[n] = v;                                  // buf[0]
    } else if (gid < N_NODES + NBUF) {
        // zero sentinel word in every ring buffer (masked-off edges point here)
        bufs[(size_t)(gid - N_NODES) * strw + N_NODES] = 0ull;
    } else if (gid < N_NODES + NBUF + T_STEPS * INPUT_BITS) {
        int k = gid - (N_NODES + NBUF);
        int t = k >> 6, j = k & 63;
        uint64_t m = 0ull;
        for (int b = 0; b < BATCH; ++b)
            m |= (uint64_t)(x[b * (T_STEPS * INPUT_BITS) + t * INPUT_BITS + j] & 1) << b;
        xmask[k] = m;
    } else {
        int c = gid - (N_NODES + NBUF + T_STEPS * INPUT_BITS);
        if (c < T_STEPS * GRPN) gctr[c * 64] = 0;                   // replay-safe
        else if (c < T_STEPS * GRPN + T_STEPS)
            rctr[(c - T_STEPS * GRPN) * 64] = 0;
    }
}

// ---------------- pack LUT to bits (full-GPU, HBM-bound): 204.8 MB -> 6.4 MB ----------------
__global__ void lutpack_kernel(const int* __restrict__ lut,
                               uint64_t* __restrict__ plut) {
    const int tid = threadIdx.x;
    const int blk = blockIdx.x;                  // node
    const int lane = tid & 63, wave = tid >> 6;  // 16 waves x 64 lanes = 1024 entries
    int v = lut[(size_t)blk * 1024 + tid];
    uint64_t m = __ballot(v & 1);
    if (lane == 0) plut[(size_t)blk * 16 + wave] = m;
}

// ---------------- cooperative kernel: all 32 steps ----------------
__global__ __launch_bounds__(NTHR)
void reservoir_coop(const uint64_t* __restrict__ plut,
                    const int* __restrict__ adj,
                    const int* __restrict__ adjmask,
                    const int* __restrict__ input_nodes,
                    const uint64_t* __restrict__ xmask,
                    uint64_t* __restrict__ bufs,
                    uint32_t* __restrict__ gctr,
                    uint32_t* __restrict__ rctr) {
    __shared__ uint8_t lutb[NPW * 128];   // 28 KB: this WG's bit-packed LUT rows

    const int tid = threadIdx.x;
    const int wg  = blockIdx.x;
    const int grp = wg >> 4;              // 0..13 (16 WGs per group)

    // ---- stage packed LUT slice -> LDS (coalesced, 32 B/thread) ----
    {
        const uint4* s = (const uint4*)(plut + (size_t)wg * NPW * 16);
        uint4* d = (uint4*)lutb;
        d[tid]        = s[tid];
        d[tid + NTHR] = s[tid + NTHR];
    }

    // ---- persistent per-thread setup (registers for all 32 steps) ----
    const int nl   = tid >> 2;            // local node (0..223)
    const int q    = tid & 3;             // batch quarter (16 batches)
    const int lane = tid & 63;
    const int node = wg * NPW + nl;
    const bool valid = node < N_NODES;
    const uint32_t qsh = (uint32_t)(q & 1) * 16;

    // gather duty: lane q of each node quad fetches neighbor WORDS (uint64,
    // all 64 batches) k = q, q+4, and (q<2) q+8; sentinel word N_NODES for
    // masked-off/unused slots (always 0, L2-hot).
    uint32_t goff0 = N_NODES, goff1 = N_NODES, goff2 = N_NODES;   // u64-word indices
    uint32_t soff = 0;                    // store dword byte offset (even-q lanes)
    int jm = -1;
    if (valid) {
        int a, mk;
        a = adj[node * K_MAX + q];      mk = adjmask[node * K_MAX + q];
        goff0 = mk ? (uint32_t)a : (uint32_t)N_NODES;
        a = adj[node * K_MAX + q + 4];  mk = adjmask[node * K_MAX + q + 4];
        goff1 = mk ? (uint32_t)a : (uint32_t)N_NODES;
        if (q < 2) {
            a = adj[node * K_MAX + q + 8]; mk = adjmask[node * K_MAX + q + 8];
            goff2 = mk ? (uint32_t)a : (uint32_t)N_NODES;
        }
        for (int j = 0; j < INPUT_BITS; ++j)
            if (input_nodes[j] == node) jm = j;   // last occurrence
        soff = (uint32_t)node * 8u + (uint32_t)(q >> 1) * 4u;
    }
    const uint32_t* lut32 = (const uint32_t*)lutb;
    const uint32_t* xm32  = (const uint32_t*)xmask;
    const int rowbase = nl * 32;          // dword index of this node's LDS LUT row
    const int dlbase  = lane & ~3;        // lane of q=0 in this node quad
    __syncthreads();                      // LDS staging complete

    for (int t = 0; t < T_STEPS; ++t) {
        // step t: read buf[t] (plain cached loads; ring guarantees freshness),
        //         write buf[t+1] (agent-scope, visible at L3).
        const uint64_t* s64 = (const uint64_t*)((const char*)bufs + (size_t)t * BUF_STRIDE_B);
        char*           dst = (char*)bufs + (size_t)(t + 1) * BUF_STRIDE_B;

        // ---- gather: 2-3 uint64 per lane (500K L2 requests/step total, 4x cut) ----
        uint64_t g0 = s64[goff0];
        uint64_t g1 = s64[goff1];
        uint64_t g2 = s64[goff2];
        uint32_t v0 = (uint32_t)g0, v1 = (uint32_t)(g0 >> 32);
        uint32_t v2 = (uint32_t)g1, v3 = (uint32_t)(g1 >> 32);
        uint32_t v4 = (uint32_t)g2, v5 = (uint32_t)(g2 >> 32);

        // ---- in-wave redistribute: w[k] = 16-bit batch slice of neighbor k ----
        uint32_t w[K_MAX];
        #pragma unroll
        for (int k = 0; k < K_MAX; ++k) {
            int dl = dlbase | (k & 3);    // donor lane (k&3 == k-8 for k>=8)
            uint32_t lo, hi;
            if (k < 4)      { lo = v0; hi = v1; }
            else if (k < 8) { lo = v2; hi = v3; }
            else            { lo = v4; hi = v5; }
            uint32_t slo = __shfl(lo, dl);
            uint32_t shi = __shfl(hi, dl);
            w[k] = ((q & 2) ? shi : slo) >> qsh;
        }

        uint32_t o16 = 0;
        #pragma unroll
        for (int b = 0; b < 16; ++b) {
            uint32_t idx = 0;
            #pragma unroll
            for (int k = 0; k < K_MAX; ++k)
                idx = (idx << 1) | ((w[k] >> b) & 1u);   // k=0 -> MSB (pow2 order)
            uint32_t d = lut32[rowbase + (idx >> 5)];
            o16 |= ((d >> (idx & 31)) & 1u) << b;
        }

        // pair lanes (q even/odd) combine to one dword store
        uint32_t hi16 = __shfl_down(o16, 1);
        if (valid && (q & 1) == 0) {
            uint32_t o32 = o16 | (hi16 << 16);
            // fold next step's input-bit XOR into this write
            if (jm >= 0 && t < T_STEPS - 1)
                o32 ^= xm32[((t + 1) * INPUT_BITS + jm) * 2 + (q >> 1)];
            __hip_atomic_store((uint32_t*)(dst + soff), o32,
                               __ATOMIC_RELAXED, __HIP_MEMORY_SCOPE_AGENT);
        }

        if (t < T_STEPS - 1) {
            // ---- 2-level tree barrier (r8-proven) ----
            __syncthreads();
            if (tid == 0) {
                uint32_t* gc = gctr + ((size_t)t * GRPN + grp) * 64;
                uint32_t* rc = rctr + (size_t)t * 64;
                uint32_t old = __hip_atomic_fetch_add(gc, 1u, __ATOMIC_RELAXED,
                                                      __HIP_MEMORY_SCOPE_AGENT);
                if (old == GRP_SZ - 1)
                    __hip_atomic_fetch_add(rc, 1u, __ATOMIC_RELAXED,
                                           __HIP_MEMORY_SCOPE_AGENT);
                while (__hip_atomic_load(rc, __ATOMIC_RELAXED, __HIP_MEMORY_SCOPE_AGENT)
                       < (uint32_t)GRPN)
                    __builtin_amdgcn_s_sleep(1);
            }
            __syncthreads();
        }
    }
}

// ---------------- output: out[b,i] = sum_n state[b,n]*W[i,n] + bias[i] ----------------
__global__ void out_kernel(const uint64_t* __restrict__ fstate,
                           const float* __restrict__ W,
                           const float* __restrict__ bias,
                           float* __restrict__ out) {
    const int wg = blockIdx.x;          // b*16 + i
    const int b = wg >> 4, i = wg & 15;
    const int tid = threadIdx.x;
    const uint8_t* st = (const uint8_t*)fstate;
    const int byteoff = b >> 3, bsh = b & 7;

    float s = 0.f;
    for (int n = tid; n < N_NODES; n += 256) {
        uint32_t bit = (st[(size_t)n * 8 + byteoff] >> bsh) & 1u;
        s += (float)bit * W[(size_t)i * N_NODES + n];
    }
    #pragma unroll
    for (int off = 32; off; off >>= 1) s += __shfl_down(s, off);

    __shared__ float part[4];
    const int lane = tid & 63, wave = tid >> 6;
    if (lane == 0) part[wave] = s;
    __syncthreads();
    if (tid == 0) out[wg] = part[0] + part[1] + part[2] + part[3] + bias[i];
}

extern "C" void kernel_launch(void* const* d_in, const int* in_sizes, int n_in,
                              void* d_out, int out_size, void* d_ws, size_t ws_size,
                              hipStream_t stream) {
    const int*   x       = (const int*)d_in[0];
    const int*   adj     = (const int*)d_in[1];
    const int*   adjmask = (const int*)d_in[2];
    const int*   lut     = (const int*)d_in[3];
    const int*   initst  = (const int*)d_in[4];
    const int*   innodes = (const int*)d_in[5];
    const float* W       = (const float*)d_in[6];
    const float* bias    = (const float*)d_in[7];
    float* out = (float*)d_out;

    char* ws = (char*)d_ws;
    uint64_t* bufs  = (uint64_t*)(ws + OFF_BUFS);
    uint64_t* xmask = (uint64_t*)(ws + OFF_XMASK);
    uint32_t* gctr  = (uint32_t*)(ws + OFF_GCTR);
    uint32_t* rctr  = (uint32_t*)(ws + OFF_RCTR);
    uint64_t* plut  = (uint64_t*)(ws + OFF_PLUT);

    {
        int prep_threads = N_NODES + NBUF + T_STEPS * INPUT_BITS
                         + T_STEPS * GRPN + T_STEPS;
        int prep_blocks = (prep_threads + 255) / 256;
        hipLaunchKernelGGL(prep_kernel, dim3(prep_blocks), dim3(256), 0, stream,
                           x, initst, innodes, bufs, xmask, gctr, rctr);
    }

    hipLaunchKernelGGL(lutpack_kernel, dim3(N_NODES), dim3(1024), 0, stream, lut, plut);

    {
        void* args[] = { (void*)&plut, (void*)&adj, (void*)&adjmask, (void*)&innodes,
                         (void*)&xmask, (void*)&bufs, (void*)&gctr, (void*)&rctr };
        hipLaunchCooperativeKernel((void*)reservoir_coop,
                                   dim3(NWG), dim3(NTHR),
                                   args, 0, stream);
    }

    // final states live in buf[32]
    hipLaunchKernelGGL(out_kernel, dim3(BATCH * N_INPUTS), dim3(256), 0, stream,
                       (const uint64_t*)(ws + OFF_BUFS + (size_t)T_STEPS * BUF_STRIDE_B),
                       W, bias, out);
}

// Round 11
// 384.205 us; speedup vs baseline: 1.0006x; 1.0006x over previous
//
#include <hip/hip_runtime.h>
#include <stdint.h>

#define N_NODES    50000
#define K_MAX      10
#define BATCH      64
#define T_STEPS    32
#define N_INPUTS   16
#define INPUT_BITS 64

#define NPW   98                  // nodes per workgroup
#define NWG   512                 // 32 groups x 16; 2 WGs/CU (r7-proven geometry)
#define NTHR  448                 // 7 waves; 4 threads (batch quarters) per node
#define GRPN  32                  // barrier tree: 32 groups
#define GRP_SZ 16                 //   of 16 WGs each
#define NBUF  (T_STEPS + 1)       // state ring: step t reads buf[t], writes buf[t+1]

#define BUF_STRIDE_B 400128u      // bytes per state buffer (50001*8 -> 128B aligned)

// ---------------- workspace layout (bytes) ----------------
#define OFF_BUFS   0u
#define OFF_XMASK  13204224u      // uint64[32*64]
#define OFF_GCTR   13220608u      // 32 steps x 32 group ctrs, each on own 256B line
#define OFF_RCTR   13482752u      // 32 root ctrs, each on own 256B line
// end 13490944 B (~13.5 MB, no plut buffer anymore)

// ---------------- prep: init ring head, xor masks, sentinels, barrier ctrs ----------------
__global__ void prep_kernel(const int* __restrict__ x,
                            const int* __restrict__ init_states,
                            const int* __restrict__ input_nodes,
                            uint64_t* __restrict__ bufs,
                            uint64_t* __restrict__ xmask,
                            uint32_t* __restrict__ gctr,
                            uint32_t* __restrict__ rctr) {
    const int gid = blockIdx.x * blockDim.x + threadIdx.x;
    const size_t strw = BUF_STRIDE_B / 8;
    if (gid < N_NODES) {
        int n = gid;
        // last occurrence of n in input_nodes (last-write-wins scatter semantics)
        int jm = -1;
        for (int j = 0; j < INPUT_BITS; ++j)
            if (input_nodes[j] == n) jm = j;
        uint64_t v = init_states[n] ? ~0ull : 0ull;   // same init for all 64 batches
        if (jm >= 0) {
            uint64_t m = 0ull;
            for (int b = 0; b < BATCH; ++b)
                m |= (uint64_t)(x[b * (T_STEPS * INPUT_BITS) + jm] & 1) << b;  // t = 0
            v ^= m;
        }
        bufs[n] = v;                                  // buf[0]
    } else if (gid < N_NODES + NBUF) {
        // zero sentinel word in every ring buffer (masked-off edges point here)
        bufs[(size_t)(gid - N_NODES) * strw + N_NODES] = 0ull;
    } else if (gid < N_NODES + NBUF + T_STEPS * INPUT_BITS) {
        int k = gid - (N_NODES + NBUF);
        int t = k >> 6, j = k & 63;
        uint64_t m = 0ull;
        for (int b = 0; b < BATCH; ++b)
            m |= (uint64_t)(x[b * (T_STEPS * INPUT_BITS) + t * INPUT_BITS + j] & 1) << b;
        xmask[k] = m;
    } else {
        int c = gid - (N_NODES + NBUF + T_STEPS * INPUT_BITS);
        if (c < T_STEPS * GRPN) gctr[c * 64] = 0;                   // replay-safe
        else if (c < T_STEPS * GRPN + T_STEPS)
            rctr[(c - T_STEPS * GRPN) * 64] = 0;
    }
}

// ---------------- cooperative kernel: in-LDS LUT pack + all 32 steps ----------------
__global__ __launch_bounds__(NTHR)
void reservoir_coop(const int* __restrict__ adj,
                    const int* __restrict__ adjmask,
                    const int* __restrict__ lut,
                    const int* __restrict__ input_nodes,
                    const uint64_t* __restrict__ xmask,
                    uint64_t* __restrict__ bufs,
                    uint32_t* __restrict__ gctr,
                    uint32_t* __restrict__ rctr) {
    __shared__ uint8_t lutb[NPW * 128];   // 12.25 KB: this WG's bit-packed LUT rows

    const int tid  = threadIdx.x;
    const int wg   = blockIdx.x;
    const int grp  = wg >> 4;             // 0..31 (16 WGs per group)
    const int lane = tid & 63;
    const int wv   = tid >> 6;            // 7 waves

    // ---- pack LUT rows straight into LDS (r3-proven ballot pattern, full-GPU) ----
    // wave wv packs rows [wv*14, wv*14+14)  (7 waves x 14 = 98 rows)
    for (int rr = 0; rr < 14; ++rr) {
        int r  = wv * 14 + rr;
        int gn = wg * NPW + r;
        if (gn < N_NODES) {
            uint64_t mine = 0ull;
            #pragma unroll
            for (int c = 0; c < 16; ++c) {
                int v = lut[(size_t)gn * 1024 + (size_t)c * 64 + lane];
                uint64_t m = __ballot(v & 1);
                if (lane == c) mine = m;      // lane c keeps word c
            }
            if (lane < 16) ((uint64_t*)lutb)[r * 16 + lane] = mine;
        }
    }

    // ---- persistent per-thread setup (registers for all 32 steps) ----
    const int nl   = tid >> 2;            // local node (0..111; only <98 valid)
    const int q    = tid & 3;             // batch quarter (16 batches)
    const int node = wg * NPW + nl;
    const bool valid = (nl < NPW) && (node < N_NODES);
    const uint32_t qsh = (uint32_t)(q & 1) * 16;

    uint32_t off[K_MAX];                  // gather dword byte offsets (buffer-relative)
    uint32_t soff = 0;
    int jm = -1;
    #pragma unroll
    for (int k = 0; k < K_MAX; ++k)       // sentinel default (always-0 word)
        off[k] = (uint32_t)N_NODES * 8u + (uint32_t)(q >> 1) * 4u;
    if (valid) {
        #pragma unroll
        for (int k = 0; k < K_MAX; ++k) {
            int a  = adj[node * K_MAX + k];
            int mk = adjmask[node * K_MAX + k];
            off[k] = (uint32_t)(mk ? a : N_NODES) * 8u + (uint32_t)(q >> 1) * 4u;
        }
        for (int j = 0; j < INPUT_BITS; ++j)
            if (input_nodes[j] == node) jm = j;   // last occurrence
        soff = (uint32_t)node * 8u + (uint32_t)(q >> 1) * 4u;
    }
    const uint32_t* lut32 = (const uint32_t*)lutb;
    const uint32_t* xm32  = (const uint32_t*)xmask;
    const int rowbase = nl * 32;          // dword index of this node's LDS LUT row
    __syncthreads();                      // LDS pack complete

    for (int t = 0; t < T_STEPS; ++t) {
        // step t: read buf[t] (plain cached loads; ring guarantees freshness),
        //         write buf[t+1] (agent-scope, visible at L3).
        const char* src = (const char*)bufs + (size_t)t * BUF_STRIDE_B;
        char*       dst = (char*)bufs + (size_t)(t + 1) * BUF_STRIDE_B;

        uint32_t w[K_MAX];
        #pragma unroll
        for (int k = 0; k < K_MAX; ++k)
            w[k] = *(const uint32_t*)(src + off[k]) >> qsh;

        uint32_t o16 = 0;
        #pragma unroll
        for (int b = 0; b < 16; ++b) {
            uint32_t idx = 0;
            #pragma unroll
            for (int k = 0; k < K_MAX; ++k)
                idx = (idx << 1) | ((w[k] >> b) & 1u);   // k=0 -> MSB (pow2 order)
            uint32_t d = lut32[rowbase + (idx >> 5)];
            o16 |= ((d >> (idx & 31)) & 1u) << b;
        }

        // pair lanes (q even/odd) combine to one dword store
        uint32_t hi16 = __shfl_down(o16, 1);
        if (valid && (q & 1) == 0) {
            uint32_t o32 = o16 | (hi16 << 16);
            // fold next step's input-bit XOR into this write
            if (jm >= 0 && t < T_STEPS - 1)
                o32 ^= xm32[((t + 1) * INPUT_BITS + jm) * 2 + (q >> 1)];
            __hip_atomic_store((uint32_t*)(dst + soff), o32,
                               __ATOMIC_RELAXED, __HIP_MEMORY_SCOPE_AGENT);
        }

        if (t < T_STEPS - 1) {
            // ---- 2-level tree barrier (r8-proven; 32 parallel group lines) ----
            __syncthreads();              // drains vmcnt: sc1 stores L3-visible
            if (tid == 0) {
                uint32_t* gc = gctr + ((size_t)t * GRPN + grp) * 64;
                uint32_t* rc = rctr + (size_t)t * 64;
                uint32_t old = __hip_atomic_fetch_add(gc, 1u, __ATOMIC_RELAXED,
                                                      __HIP_MEMORY_SCOPE_AGENT);
                if (old == GRP_SZ - 1)
                    __hip_atomic_fetch_add(rc, 1u, __ATOMIC_RELAXED,
                                           __HIP_MEMORY_SCOPE_AGENT);
                while (__hip_atomic_load(rc, __ATOMIC_RELAXED, __HIP_MEMORY_SCOPE_AGENT)
                       < (uint32_t)GRPN)
                    __builtin_amdgcn_s_sleep(1);
            }
            __syncthreads();
        }
    }
}

// ---------------- output: out[b,i] = sum_n state[b,n]*W[i,n] + bias[i] ----------------
__global__ void out_kernel(const uint64_t* __restrict__ fstate,
                           const float* __restrict__ W,
                           const float* __restrict__ bias,
                           float* __restrict__ out) {
    const int wg = blockIdx.x;          // b*16 + i
    const int b = wg >> 4, i = wg & 15;
    const int tid = threadIdx.x;
    const uint8_t* st = (const uint8_t*)fstate;
    const int byteoff = b >> 3, bsh = b & 7;

    float s = 0.f;
    for (int n = tid; n < N_NODES; n += 256) {
        uint32_t bit = (st[(size_t)n * 8 + byteoff] >> bsh) & 1u;
        s += (float)bit * W[(size_t)i * N_NODES + n];
    }
    #pragma unroll
    for (int off = 32; off; off >>= 1) s += __shfl_down(s, off);

    __shared__ float part[4];
    const int lane = tid & 63, wave = tid >> 6;
    if (lane == 0) part[wave] = s;
    __syncthreads();
    if (tid == 0) out[wg] = part[0] + part[1] + part[2] + part[3] + bias[i];
}

extern "C" void kernel_launch(void* const* d_in, const int* in_sizes, int n_in,
                              void* d_out, int out_size, void* d_ws, size_t ws_size,
                              hipStream_t stream) {
    const int*   x       = (const int*)d_in[0];
    const int*   adj     = (const int*)d_in[1];
    const int*   adjmask = (const int*)d_in[2];
    const int*   lut     = (const int*)d_in[3];
    const int*   initst  = (const int*)d_in[4];
    const int*   innodes = (const int*)d_in[5];
    const float* W       = (const float*)d_in[6];
    const float* bias    = (const float*)d_in[7];
    float* out = (float*)d_out;

    char* ws = (char*)d_ws;
    uint64_t* bufs  = (uint64_t*)(ws + OFF_BUFS);
    uint64_t* xmask = (uint64_t*)(ws + OFF_XMASK);
    uint32_t* gctr  = (uint32_t*)(ws + OFF_GCTR);
    uint32_t* rctr  = (uint32_t*)(ws + OFF_RCTR);

    {
        int prep_threads = N_NODES + NBUF + T_STEPS * INPUT_BITS
                         + T_STEPS * GRPN + T_STEPS;
        int prep_blocks = (prep_threads + 255) / 256;
        hipLaunchKernelGGL(prep_kernel, dim3(prep_blocks), dim3(256), 0, stream,
                           x, initst, innodes, bufs, xmask, gctr, rctr);
    }

    {
        void* args[] = { (void*)&adj, (void*)&adjmask, (void*)&lut, (void*)&innodes,
                         (void*)&xmask, (void*)&bufs, (void*)&gctr, (void*)&rctr };
        hipLaunchCooperativeKernel((void*)reservoir_coop,
                                   dim3(NWG), dim3(NTHR),
                                   args, 0, stream);
    }

    // final states live in buf[32]
    hipLaunchKernelGGL(out_kernel, dim3(BATCH * N_INPUTS), dim3(256), 0, stream,
                       (const uint64_t*)(ws + OFF_BUFS + (size_t)T_STEPS * BUF_STRIDE_B),
                       W, bias, out);
}